// Round 4
// baseline (339.257 us; speedup 1.0000x reference)
//
#include <hip/hip_runtime.h>
#include <cstdint>

// Problem constants (match reference)
#define TOK 2048
#define HD  1024
#define ID  768
#define NE  32
#define G1RT 2
#define G2RT 2

typedef unsigned short u16t;
typedef unsigned int   u32t;
typedef __bf16 bf16x8 __attribute__((ext_vector_type(8)));
typedef float  f32x4  __attribute__((ext_vector_type(4)));
typedef u16t   u16x8  __attribute__((ext_vector_type(8)));
typedef u16t   u16x4  __attribute__((ext_vector_type(4)));
typedef float  fvec4  __attribute__((ext_vector_type(4)));

// f32 -> bf16 round-to-nearest-even
__device__ __forceinline__ u16t f2b(float f) {
  u32t u = __float_as_uint(f);
  u32t r = u + 0x7fffu + ((u >> 16) & 1u);
  return (u16t)(r >> 16);
}

// async global -> LDS, 16B per lane (dest = wave-uniform base + lane*16)
typedef __attribute__((address_space(3))) unsigned int       lds_uint;
typedef const __attribute__((address_space(1))) unsigned int glob_uint;
__device__ __forceinline__ void gload16(const void* g, void* l) {
  __builtin_amdgcn_global_load_lds((glob_uint*)g, (lds_uint*)l, 16, 0, 0);
}

// ---- LDS geometry -----------------------------------------------------------
// X tile (128 rows x 32 k bf16): granule-striped [g][row], stripe pitch
// 1056 u16 (2112 B, +64B pad): row r granule g at u16 off g*1056 + r*8.
// gload writes stripe g linearly (lane=row); pad spreads banks ~4-way on read.
#define XS_BUF   4224            // u16 per buffer (4 stripes)
#define XS_G     1056
// W tile (64 cols x 32 k bf16): k-granule-major [kc][col], stripe pitch
// 544 u16 (1088 B): col c granule kc at u16 off kc*544 + c*8. ~4-way reads.
#define WS_KC    544
#define WS_MAT   2176            // u16 per (buf,mat)
#define WS_BUF   4352            // u16 per buffer (2 mats)

// ---------------------------------------------------------------- k_cvt ----
__global__ void k_cvt(const float* __restrict__ x, u16t* __restrict__ xb) {
  int i = (blockIdx.x * 256 + threadIdx.x) * 4;
  fvec4 v = *(const fvec4*)(x + i);
  u16x4 o = { f2b(v[0]), f2b(v[1]), f2b(v[2]), f2b(v[3]) };
  *(u16x4*)(xb + i) = o;
}

// -------------------------------------------------------------- k_router ---
__global__ void k_router(const float* __restrict__ x, const float* __restrict__ gw,
                         const float* __restrict__ eb,
                         int* __restrict__ topk_ids, float* __restrict__ topk_w,
                         int* __restrict__ counts) {
  int lane = threadIdx.x & 63;
  int t = blockIdx.x * 4 + (threadIdx.x >> 6);
  const float* xt = x + (size_t)t * HD;
  fvec4 xr[4];
#pragma unroll
  for (int i = 0; i < 4; ++i) xr[i] = *(const fvec4*)(xt + lane * 4 + i * 256);
  float myscore = 0.f;
  for (int e = 0; e < NE; ++e) {
    const float* ge = gw + (size_t)e * HD + lane * 4;
    float s = 0.f;
#pragma unroll
    for (int i = 0; i < 4; ++i) {
      fvec4 g = *(const fvec4*)(ge + i * 256);
      s = fmaf(xr[i][0], g[0], s); s = fmaf(xr[i][1], g[1], s);
      s = fmaf(xr[i][2], g[2], s); s = fmaf(xr[i][3], g[3], s);
    }
#pragma unroll
    for (int off = 32; off; off >>= 1) s += __shfl_xor(s, off);
    if (lane == e) myscore = s;
  }
  float sig = 1.f / (1.f + expf(-myscore));
  float biased = (lane < NE) ? (sig + eb[lane]) : -3.0e38f;
  float wsum = 0.f;
  int ids[4]; float wsv[4];
#pragma unroll
  for (int k = 0; k < 4; ++k) {
    float v = biased; int idx = lane;
#pragma unroll
    for (int off = 32; off; off >>= 1) {
      float ov = __shfl_xor(v, off);
      int   oi = __shfl_xor(idx, off);
      if (ov > v || (ov == v && oi < idx)) { v = ov; idx = oi; }
    }
    ids[k] = idx;
    float sc = __shfl(sig, idx);   // uncorrected sigmoid score is the weight
    wsv[k] = sc; wsum += sc;
    if (lane == idx) biased = -3.0e38f;
  }
  float inv = 1.f / wsum;
#pragma unroll
  for (int k = 0; k < 4; ++k) {
    if (lane == k) {
      topk_ids[t * 4 + k] = ids[k];
      topk_w[t * 4 + k]  = wsv[k] * inv;
      atomicAdd(&counts[ids[k]], 1);
    }
  }
}

// -------------------------------------------------------------- k_bucket ---
__global__ void k_bucket(const int* __restrict__ topk_ids, const float* __restrict__ topk_w,
                         const int* __restrict__ counts, int* __restrict__ offsets,
                         int* __restrict__ pairTok, float* __restrict__ pairW,
                         int* __restrict__ invp) {
  __shared__ int soff[NE + 1];
  __shared__ int scur[NE];
  int tid = threadIdx.x;
  if (tid == 0) {
    int acc = 0;
    for (int e = 0; e < NE; ++e) { soff[e] = acc; acc += counts[e]; }
    soff[NE] = acc;
  }
  if (tid < NE) scur[tid] = 0;
  __syncthreads();
  if (tid <= NE) offsets[tid] = soff[tid];
  for (int p = tid; p < TOK * 4; p += 256) {
    int e = topk_ids[p];
    int pos = soff[e] + atomicAdd(&scur[e], 1);
    pairTok[pos] = p;          // p = t*4+k
    pairW[pos]   = topk_w[p];
    invp[p]      = pos;
  }
}

// --------------------------------------------------------------- k_gemm1 ---
// grid (12 col-tiles of 64, 32 experts, 2). 256 thr / 4 waves.
// Tile 128 rows x 64 cols; waves 0-1 compute g (w1), waves 2-3 u (w3).
// X via global_load_lds (2-buf granule-striped); W reg-staged f32->bf16 (2-buf).
// One barrier per K-step; SiLU fusion via LDS exchange in epilogue.
union SMemG1 {
  struct { u16t Xs[2 * XS_BUF]; u16t Ws[2 * WS_BUF]; } s;   // 16896B + 17408B
  float ex[128 * 64];                                        // 32768B overlay
};

#define G1_STAGEX(P, KK) do { \
    gload16(xb + (size_t)tokA * HD + (KK) + wv * 8, &sm.s.Xs[(P) * XS_BUF + wv * XS_G]); \
    gload16(xb + (size_t)tokB * HD + (KK) + wv * 8, &sm.s.Xs[(P) * XS_BUF + wv * XS_G + 512]); \
  } while (0)

#define G1_WLOAD(KK) do { \
    const float* _s = wp + (size_t)((KK) + k0) * ID + wcol; \
    wd[0] = *(const fvec4*)_s;            wd[1] = *(const fvec4*)(_s + ID); \
    wd[2] = *(const fvec4*)(_s + 2 * ID); wd[3] = *(const fvec4*)(_s + 3 * ID); \
  } while (0)

#define G1_WSTORE(P) do { \
    _Pragma("unroll") for (int c = 0; c < 4; ++c) { \
      u16x4 pk = { f2b(wd[0][c]), f2b(wd[1][c]), f2b(wd[2][c]), f2b(wd[3][c]) }; \
      *(u16x4*)&sm.s.Ws[(P) * WS_BUF + mat_s * WS_MAT + kcs * WS_KC + (cg4 + c) * 8 + koff] = pk; \
    } } while (0)

#define G1_MFMA(P) do { \
    const int _x = (P) * XS_BUF + kcl * XS_G; \
    bf16x8 af[4]; \
    _Pragma("unroll") for (int rf = 0; rf < 4; ++rf) \
      af[rf] = *(const bf16x8*)&sm.s.Xs[_x + (rb + rf * 16) * 8]; \
    const int _w = (P) * WS_BUF + mat * WS_MAT + kcl * WS_KC; \
    _Pragma("unroll") for (int cf = 0; cf < 4; ++cf) { \
      bf16x8 b = *(const bf16x8*)&sm.s.Ws[_w + (cf * 16 + l15) * 8]; \
      _Pragma("unroll") for (int rf = 0; rf < 4; ++rf) \
        acc[rf][cf] = __builtin_amdgcn_mfma_f32_16x16x32_bf16(af[rf], b, acc[rf][cf], 0, 0, 0); \
    } } while (0)

__launch_bounds__(256, 4)
__global__ void k_gemm1(const u16t* __restrict__ xb, const float* __restrict__ w1,
                        const float* __restrict__ w3,
                        const int* __restrict__ counts, const int* __restrict__ offsets,
                        const int* __restrict__ pairTok, const float* __restrict__ pairW,
                        u16t* __restrict__ A) {
  const int e = blockIdx.y;
  const int colbase = blockIdx.x * 64;
  const int count = counts[e];
  const int base  = offsets[e];
  const int tid = threadIdx.x, lane = tid & 63, wv = tid >> 6;
  const int mat = wv >> 1, half = wv & 1;        // compute role
  const int l15 = lane & 15, kcl = lane >> 4;
  const int rb = half * 64 + l15;

  __shared__ SMemG1 sm;
  __shared__ float pw[128];

  // W staging role (independent of compute role)
  const int mat_s = tid >> 7;
  const float* wp = (mat_s ? w3 : w1) + (size_t)e * HD * ID;
  const int u = tid & 127;
  const int cg4 = (u & 15) * 4, hg = u >> 4;     // 4 cols, 4 k-rows per thread
  const int k0 = hg * 4, kcs = hg >> 1, koff = (hg & 1) * 4;
  const int wcol = colbase + cg4;

  for (int r0 = blockIdx.z * 128; r0 < count; r0 += G1RT * 128) {
    __syncthreads();   // prev epilogue readers done (ex overlays staging LDS)
    if (tid < 128) pw[tid] = (r0 + tid < count) ? pairW[base + r0 + tid] : 0.f;
    int ia = r0 + lane;       ia = ia < count ? ia : count - 1;
    int ib = r0 + 64 + lane;  ib = ib < count ? ib : count - 1;
    const int tokA = pairTok[base + ia] >> 2;
    const int tokB = pairTok[base + ib] >> 2;

    f32x4 zz = {0.f, 0.f, 0.f, 0.f};
    f32x4 acc[4][4];
#pragma unroll
    for (int a = 0; a < 4; ++a)
#pragma unroll
      for (int b = 0; b < 4; ++b) acc[a][b] = zz;

    fvec4 wd[4];
    // prologue: stage step 0, prefetch W(1)
    G1_STAGEX(0, 0);
    G1_WLOAD(0);
    G1_WSTORE(0);
    G1_WLOAD(32);
    __syncthreads();

    for (int s = 0; s < 32; ++s) {
      const int p = s & 1;
      if (s < 31) { G1_STAGEX(p ^ 1, s * 32 + 32); G1_WSTORE(p ^ 1); }
      if (s < 30) G1_WLOAD(s * 32 + 64);
      G1_MFMA(p);
      __syncthreads();
    }

    // epilogue: waves 2-3 publish u; waves 0-1 fuse silu(g)*u*pw -> A
    if (mat == 1) {
#pragma unroll
      for (int rf = 0; rf < 4; ++rf)
#pragma unroll
        for (int ri = 0; ri < 4; ++ri) {
          int row = half * 64 + rf * 16 + (lane >> 4) * 4 + ri;
#pragma unroll
          for (int cf = 0; cf < 4; ++cf)
            sm.ex[row * 64 + cf * 16 + l15] = acc[rf][cf][ri];
        }
    }
    __syncthreads();
    if (mat == 0) {
#pragma unroll
      for (int rf = 0; rf < 4; ++rf)
#pragma unroll
        for (int ri = 0; ri < 4; ++ri) {
          int row = half * 64 + rf * 16 + (lane >> 4) * 4 + ri;
          int grow = r0 + row;
          if (grow < count) {
            float wgt = pw[row];
#pragma unroll
            for (int cf = 0; cf < 4; ++cf) {
              float gg = acc[rf][cf][ri];
              float uu = sm.ex[row * 64 + cf * 16 + l15];
              float a = gg / (1.f + expf(-gg)) * uu * wgt;
              A[(size_t)(base + grow) * ID + colbase + cf * 16 + l15] = f2b(a);
            }
          }
        }
    }
  }
}

// --------------------------------------------------------------- k_gemm2 ---
// grid (16 col-tiles of 64, 32 experts, 2). Tile 128 x 64, 4 waves x 32 rows.
#define G2_STAGEA(P, KK) do { \
    gload16(Ab + (size_t)arowA * ID + (KK) + wv * 8, &Xs[(P) * XS_BUF + wv * XS_G]); \
    gload16(Ab + (size_t)arowB * ID + (KK) + wv * 8, &Xs[(P) * XS_BUF + wv * XS_G + 512]); \
  } while (0)

#define G2_WLOAD(KK) do { \
    const float* _s = w2e + (size_t)((KK) + k0) * HD + wcol; \
    wd[0] = *(const fvec4*)_s; wd[1] = *(const fvec4*)(_s + HD); \
  } while (0)

#define G2_WSTORE(P) do { \
    _Pragma("unroll") for (int c = 0; c < 4; ++c) { \
      u32t pk = (u32t)f2b(wd[0][c]) | ((u32t)f2b(wd[1][c]) << 16); \
      *(u32t*)&W2s[(P) * WS_MAT + kcs * WS_KC + (cg4 + c) * 8 + koff] = pk; \
    } } while (0)

#define G2_MFMA(P) do { \
    const int _x = (P) * XS_BUF + kcl * XS_G; \
    bf16x8 af[2]; \
    _Pragma("unroll") for (int rf = 0; rf < 2; ++rf) \
      af[rf] = *(const bf16x8*)&Xs[_x + (rb + rf * 16) * 8]; \
    const int _w = (P) * WS_MAT + kcl * WS_KC; \
    _Pragma("unroll") for (int cf = 0; cf < 4; ++cf) { \
      bf16x8 b = *(const bf16x8*)&W2s[_w + (cf * 16 + l15) * 8]; \
      _Pragma("unroll") for (int rf = 0; rf < 2; ++rf) \
        acc[rf][cf] = __builtin_amdgcn_mfma_f32_16x16x32_bf16(af[rf], b, acc[rf][cf], 0, 0, 0); \
    } } while (0)

__launch_bounds__(256, 5)
__global__ void k_gemm2(const u16t* __restrict__ Ab, const float* __restrict__ w2,
                        const int* __restrict__ counts, const int* __restrict__ offsets,
                        float* __restrict__ buf) {
  const int e = blockIdx.y;
  const int colbase = blockIdx.x * 64;
  const int count = counts[e];
  const int base  = offsets[e];
  const int tid = threadIdx.x, lane = tid & 63, wv = tid >> 6;
  const int l15 = lane & 15, kcl = lane >> 4;
  const int rb = wv * 32 + l15;

  __shared__ __align__(16) u16t Xs[2 * XS_BUF];
  __shared__ __align__(16) u16t W2s[2 * WS_MAT];

  const float* w2e = w2 + (size_t)e * ID * HD;
  const int cg4 = (tid & 15) * 4, hg = tid >> 4;   // 4 cols, 2 k-rows/thread
  const int k0 = hg * 2, kcs = hg >> 2, koff = (hg & 3) * 2;
  const int wcol = colbase + cg4;

  for (int r0 = blockIdx.z * 128; r0 < count; r0 += G2RT * 128) {
    int ia = r0 + lane;       ia = ia < count ? ia : count - 1;
    int ib = r0 + 64 + lane;  ib = ib < count ? ib : count - 1;
    const int arowA = base + ia, arowB = base + ib;

    f32x4 zz = {0.f, 0.f, 0.f, 0.f};
    f32x4 acc[2][4];
#pragma unroll
    for (int a = 0; a < 2; ++a)
#pragma unroll
      for (int b = 0; b < 4; ++b) acc[a][b] = zz;

    fvec4 wd[2];
    G2_STAGEA(0, 0);
    G2_WLOAD(0);
    G2_WSTORE(0);
    G2_WLOAD(32);
    __syncthreads();

    for (int s = 0; s < 24; ++s) {
      const int p = s & 1;
      if (s < 23) { G2_STAGEA(p ^ 1, s * 32 + 32); G2_WSTORE(p ^ 1); }
      if (s < 22) G2_WLOAD(s * 32 + 64);
      G2_MFMA(p);
      __syncthreads();
    }

#pragma unroll
    for (int rf = 0; rf < 2; ++rf)
#pragma unroll
      for (int ri = 0; ri < 4; ++ri) {
        int row = wv * 32 + rf * 16 + (lane >> 4) * 4 + ri;
        int grow = r0 + row;
        if (grow < count) {
#pragma unroll
          for (int cf = 0; cf < 4; ++cf)
            buf[(size_t)(base + grow) * HD + colbase + cf * 16 + l15] = acc[rf][cf][ri];
        }
      }
    __syncthreads();   // LDS safe for next r0 staging
  }
}

// -------------------------------------------------------------- k_reduce ---
__global__ void k_reduce(const float* __restrict__ buf, const int* __restrict__ invp,
                         float* __restrict__ out) {
  int t = blockIdx.x;
  int col = threadIdx.x * 4;
  int p0 = invp[t * 4 + 0], p1 = invp[t * 4 + 1];
  int p2 = invp[t * 4 + 2], p3 = invp[t * 4 + 3];
  fvec4 s = *(const fvec4*)(buf + (size_t)p0 * HD + col);
  s += *(const fvec4*)(buf + (size_t)p1 * HD + col);
  s += *(const fvec4*)(buf + (size_t)p2 * HD + col);
  s += *(const fvec4*)(buf + (size_t)p3 * HD + col);
  *(fvec4*)(out + (size_t)t * HD + col) = s;
}

// ------------------------------------------------------------------ host ---
extern "C" void kernel_launch(void* const* d_in, const int* in_sizes, int n_in,
                              void* d_out, int out_size, void* d_ws, size_t ws_size,
                              hipStream_t stream) {
  const float* x  = (const float*)d_in[0];
  const float* gw = (const float*)d_in[1];
  const float* w1 = (const float*)d_in[2];
  const float* w3 = (const float*)d_in[3];
  const float* w2 = (const float*)d_in[4];
  const float* eb = (const float*)d_in[5];
  float* out = (float*)d_out;

  char* ws = (char*)d_ws;
  int*   counts   = (int*)(ws);               // [32]   (zeroed)
  int*   offsets  = (int*)(ws + 256);         // [33]
  int*   topk_ids = (int*)(ws + 4096);        // [8192]
  float* topk_w   = (float*)(ws + 36864);     // [8192]
  int*   pairTok  = (int*)(ws + 69632);       // [8192]
  float* pairW    = (float*)(ws + 102400);    // [8192]
  int*   invp     = (int*)(ws + 135168);      // [8192]
  u16t*  xb       = (u16t*)(ws + 262144);                 // [2048*1024] bf16
  u16t*  Abuf     = (u16t*)(ws + 262144 + 4194304);       // [8192*768]  bf16
  float* buf      = (float*)(ws + 262144 + 4194304 + 12582912); // [8192*1024] f32

  hipMemsetAsync(counts, 0, 4096, stream);
  k_cvt   <<<2048, 256, 0, stream>>>(x, xb);
  k_router<<<512, 256, 0, stream>>>(x, gw, eb, topk_ids, topk_w, counts);
  k_bucket<<<1, 256, 0, stream>>>(topk_ids, topk_w, counts, offsets, pairTok, pairW, invp);
  k_gemm1 <<<dim3(12, 32, G1RT), 256, 0, stream>>>(xb, w1, w3, counts, offsets, pairTok, pairW, Abuf);
  k_gemm2 <<<dim3(16, 32, G2RT), 256, 0, stream>>>(Abuf, w2, counts, offsets, buf);
  k_reduce<<<2048, 256, 0, stream>>>(buf, invp, out);
}